// Round 1
// baseline (76.400 us; speedup 1.0000x reference)
//
#include <hip/hip_runtime.h>

// SeriesDecomp: x (32, 512, 2048) f32. Moving average, K=2049, replicate pad p=1024.
// Outputs: x_s = x - x_t (first N elems of d_out), x_t = movavg (next N elems).
//
// Per row closed form via inclusive prefix sum pfx[] of the row:
//   window for output i covers padded positions [i, i+2048]
//   i <  1024: wsum = (1024-i)*x[0] + pfx[i+1024]
//   i >= 1024: wsum = (i-1023)*x[L-1] + (total - (i>1024 ? pfx[i-1025] : 0))
//   x_t[i] = wsum / 2049;  x_s[i] = x[i] - x_t[i]

#define ROWLEN 2048

__global__ __launch_bounds__(256) void series_decomp_kernel(
    const float* __restrict__ x,
    float* __restrict__ xs_out,
    float* __restrict__ xt_out)
{
    __shared__ float sx[ROWLEN];    // original row
    __shared__ float pfx[ROWLEN];   // inclusive prefix sums
    __shared__ float wsum4[4];      // per-wave totals

    const int t = threadIdx.x;
    const size_t rowoff = (size_t)blockIdx.x * ROWLEN;

    // Load 8 contiguous floats per thread (2x float4), stash row in LDS.
    const float4* xin = reinterpret_cast<const float4*>(x + rowoff);
    float4 a = xin[2 * t];
    float4 b = xin[2 * t + 1];
    reinterpret_cast<float4*>(sx)[2 * t]     = a;
    reinterpret_cast<float4*>(sx)[2 * t + 1] = b;

    // In-register inclusive scan of the 8 elements.
    float s[8];
    s[0] = a.x;
    s[1] = s[0] + a.y;
    s[2] = s[1] + a.z;
    s[3] = s[2] + a.w;
    s[4] = s[3] + b.x;
    s[5] = s[4] + b.y;
    s[6] = s[5] + b.z;
    s[7] = s[6] + b.w;
    const float tot = s[7];

    // Wave (64-lane) inclusive shuffle scan of per-thread totals.
    const int lane = t & 63;
    float sc = tot;
    #pragma unroll
    for (int d = 1; d < 64; d <<= 1) {
        float o = __shfl_up(sc, d, 64);
        if (lane >= d) sc += o;
    }
    const int wid = t >> 6;
    if (lane == 63) wsum4[wid] = sc;
    __syncthreads();

    // Exclusive prefix for this thread's first element.
    float base = sc - tot;
    #pragma unroll
    for (int w = 0; w < 3; ++w)
        if (w < wid) base += wsum4[w];

    // Publish full prefix array.
    float4 p0 = make_float4(base + s[0], base + s[1], base + s[2], base + s[3]);
    float4 p1 = make_float4(base + s[4], base + s[5], base + s[6], base + s[7]);
    reinterpret_cast<float4*>(pfx)[2 * t]     = p0;
    reinterpret_cast<float4*>(pfx)[2 * t + 1] = p1;
    __syncthreads();

    const float x0    = sx[0];
    const float xl    = sx[ROWLEN - 1];
    const float total = pfx[ROWLEN - 1];
    const float invK  = 1.0f / 2049.0f;

    float* xs_row = xs_out + rowoff;
    float* xt_row = xt_out + rowoff;

    // Stride-256 consume: LDS reads lane-consecutive (conflict-free),
    // global stores coalesced 4B/lane. Branch is wave-uniform per k.
    #pragma unroll
    for (int k = 0; k < 8; ++k) {
        const int i = t + 256 * k;
        float wsum;
        if (i < 1024) {
            wsum = (float)(1024 - i) * x0 + pfx[i + 1024];
        } else {
            const int j = i - 1025;
            float pm1 = pfx[j >= 0 ? j : 0];
            if (j < 0) pm1 = 0.0f;      // only i==1024 (t==0, k==4)
            wsum = (float)(i - 1023) * xl + (total - pm1);
        }
        const float xt = wsum * invK;
        xs_row[i] = sx[i] - xt;
        xt_row[i] = xt;
    }
}

extern "C" void kernel_launch(void* const* d_in, const int* in_sizes, int n_in,
                              void* d_out, int out_size, void* d_ws, size_t ws_size,
                              hipStream_t stream) {
    const float* x = (const float*)d_in[0];
    const int n = in_sizes[0];              // 32*512*2048
    const int rows = n / ROWLEN;            // 16384
    float* xs = (float*)d_out;              // output 0: seasonal
    float* xt = (float*)d_out + (size_t)n;  // output 1: trend
    series_decomp_kernel<<<rows, 256, 0, stream>>>(x, xs, xt);
}